// Round 16
// baseline (191.219 us; speedup 1.0000x reference)
//
#include <hip/hip_runtime.h>
#include <stdint.h>

#define N_NODES 30000
#define NC 256

typedef _Float16 f16x8 __attribute__((ext_vector_type(8)));
typedef _Float16 f16x4 __attribute__((ext_vector_type(4)));
typedef _Float16 f16x2 __attribute__((ext_vector_type(2)));
typedef float f32x4 __attribute__((ext_vector_type(4)));

// ---- GEMM v11: BOTH operands LDS-staged (canonical structure) ----
// R15 post-mortem: cs-adjacent ordering was a null result (FETCH 62 MB
// unchanged) because consecutive bids round-robin across 8 XCDs with private
// L2s. Kernel remains latency-bound on in-loop A-gathers (VALU 14 / MFMA 5 /
// HBM 22 / Occ 17 -- no pipe near limit). v11: stage A into LDS exactly like
// the validated B path: one flat burst of 32 independent float4 loads/thread
// (deep MLP hides L3 latency, unlike dependent in-loop gathers), clip+cvt,
// swizzled ds_write. Inner loop all-LDS: 8 ds_read_b128 + 16 MFMA per kc.
// Kills the wq duplicate x-read too. 128 KB LDS -> 1 block/CU (12.5% occ
// ceiling) -- acceptable: steady state is LDS-throughput-bound (~3.1K cy
// compute + ~2.3K cy staging per block, ~3.7 rounds -> ~10-30 us).
#define NGB (235 * 4)
#define NPREP 118
__global__ __launch_bounds__(256, 1) void k_gemm(
    const float* __restrict__ x, const float* __restrict__ wr,
    const float* __restrict__ wi, const float* __restrict__ br,
    const float* __restrict__ bi, _Float16* __restrict__ H,
    const float* __restrict__ subH, const float* __restrict__ sub_mask,
    const float* __restrict__ escp, float* __restrict__ c4,
    float* __restrict__ ssum, float* __restrict__ ssumsq)
{
    __shared__ _Float16 As[128 * 256];        // 64KB: block's 128 x-rows, f16
    __shared__ _Float16 Bs[128 * 256];        // 64KB: rows 0..63 re, 64..127 im
    int bid = blockIdx.x;
    int tid = threadIdx.x;

    if (bid >= NGB) {
        int pb = bid - NGB;
        if (pb < NPREP) {
            // prep: P_s = esc*1e-4*subH[0][s]*mask[s]/||H||_F (clamps provably fire)
            int node = pb * 256 + tid;
            if (node < N_NODES) {
                float esc = *escp;
                const float4* Hp = reinterpret_cast<const float4*>(subH + node * 16);
                float4 r0 = Hp[0], r1 = Hp[1], r2 = Hp[2], r3 = Hp[3];
                float fr = r0.x * r0.x + r0.y * r0.y + r0.z * r0.z + r0.w * r0.w
                         + r1.x * r1.x + r1.y * r1.y + r1.z * r1.z + r1.w * r1.w
                         + r2.x * r2.x + r2.y * r2.y + r2.z * r2.z + r2.w * r2.w
                         + r3.x * r3.x + r3.y * r3.y + r3.z * r3.z + r3.w * r3.w;
                float coef = 1e-4f * rsqrtf(fr) * esc;
                float4 m = *reinterpret_cast<const float4*>(sub_mask + node * 4);
                float4 o;
                o.x = coef * r0.x * m.x;
                o.y = coef * r0.y * m.y;
                o.z = coef * r0.z * m.z;
                o.w = coef * r0.w * m.w;
                *reinterpret_cast<float4*>(c4 + node * 4) = o;
            }
        } else {
            // stats zero (feeds k_evolve's atomics)
            ssum[tid] = 0.f;
            ssumsq[tid] = 0.f;
        }
        return;
    }

    int bm = bid >> 2;                        // 0..234: row panel
    int cs = bid & 3;                         // 0..3: channel-group of 64

    // ---- stage A panel: x rows bm*128..+127, f32 -> clip -> f16, swizzled.
    // Burst of 32 independent float4 loads/thread (deep MLP). Same involution
    // swizzle as B: phys_chunk = logical_chunk ^ (row&7).
#pragma unroll
    for (int i = 0; i < 16; i++) {
        int idx = i * 256 + tid;              // 0..4095 = [row 0..127][lc 0..31]
        int row = idx >> 5;
        int lc  = idx & 31;
        int grow = bm * 128 + row;
        if (grow >= N_NODES) grow = N_NODES - 1;   // clamp: never stored
        const float* src = x + grow * 256 + lc * 8;
        float4 u = *reinterpret_cast<const float4*>(src);
        float4 v = *reinterpret_cast<const float4*>(src + 4);
        f16x8 o;
        o[0] = (_Float16)fminf(fmaxf(u.x, -10.f), 10.f);
        o[1] = (_Float16)fminf(fmaxf(u.y, -10.f), 10.f);
        o[2] = (_Float16)fminf(fmaxf(u.z, -10.f), 10.f);
        o[3] = (_Float16)fminf(fmaxf(u.w, -10.f), 10.f);
        o[4] = (_Float16)fminf(fmaxf(v.x, -10.f), 10.f);
        o[5] = (_Float16)fminf(fmaxf(v.y, -10.f), 10.f);
        o[6] = (_Float16)fminf(fmaxf(v.z, -10.f), 10.f);
        o[7] = (_Float16)fminf(fmaxf(v.w, -10.f), 10.f);
        *reinterpret_cast<f16x8*>(&As[row * 256 + (lc ^ (row & 7)) * 8]) = o;
    }

    // ---- stage B panel from f32 wr/wi (R11/R15-validated path).
#pragma unroll
    for (int i = 0; i < 16; i++) {
        int idx = i * 256 + tid;              // 0..4095
        int row = idx >> 5;                   // 0..127
        int lc  = idx & 31;                   // logical 16B chunk
        int Brow = cs * 64 + (row & 63);
        const float* wsrc = (row < 64) ? (wr + Brow * 256) : (wi + Brow * 256);
        float4 u = *reinterpret_cast<const float4*>(wsrc + lc * 8);
        float4 v = *reinterpret_cast<const float4*>(wsrc + lc * 8 + 4);
        f16x8 o;
        o[0] = (_Float16)u.x; o[1] = (_Float16)u.y;
        o[2] = (_Float16)u.z; o[3] = (_Float16)u.w;
        o[4] = (_Float16)v.x; o[5] = (_Float16)v.y;
        o[6] = (_Float16)v.z; o[7] = (_Float16)v.w;
        *reinterpret_cast<f16x8*>(&Bs[row * 256 + (lc ^ (row & 7)) * 8]) = o;
    }

    int ln = tid & 63, wv = tid >> 6;
    int quad = ln >> 4, l16 = ln & 15;
    int wm = wv >> 1, wq = wv & 1;            // wave: 64 rows x 32 channels
    int row0 = bm * 128 + wm * 64;

    // A-fragment LDS rows (block-local): arow&7 == l16&7 (64,16 mult of 8)
    int arow_f[4];
#pragma unroll
    for (int mi = 0; mi < 4; mi++)
        arow_f[mi] = wm * 64 + mi * 16 + l16;
    // B-fragment LDS rows: ni 0,1 re; 2,3 im (same channels)
    int brow_f[4];
#pragma unroll
    for (int ni = 0; ni < 4; ni++)
        brow_f[ni] = (ni < 2 ? 0 : 64) + wq * 32 + (ni & 1) * 16 + l16;

    __syncthreads();                          // As, Bs ready

    f32x4 acc[4][4] = {};
#pragma unroll
    for (int kc = 0; kc < 8; kc++) {
        int ch = (quad + kc * 4) ^ (l16 & 7);
        f16x8 af[4];
#pragma unroll
        for (int mi = 0; mi < 4; mi++)
            af[mi] = *reinterpret_cast<const f16x8*>(&As[arow_f[mi] * 256 + ch * 8]);
        f16x8 bf[4];
#pragma unroll
        for (int ni = 0; ni < 4; ni++)
            bf[ni] = *reinterpret_cast<const f16x8*>(&Bs[brow_f[ni] * 256 + ch * 8]);
#pragma unroll
        for (int mi = 0; mi < 4; mi++)
#pragma unroll
            for (int ni = 0; ni < 4; ni++)
                acc[mi][ni] = __builtin_amdgcn_mfma_f32_16x16x32_f16(
                    af[mi], bf[ni], acc[mi][ni], 0, 0, 0);
    }

    // ---- epilogue: pack (re, im) -> one 4B store, 64B contiguous per 16 lanes
#pragma unroll
    for (int ni = 0; ni < 2; ni++) {
        int c = cs * 64 + wq * 32 + ni * 16 + l16;    // channel 0..255
        float brc = br[c], bic = bi[c];
#pragma unroll
        for (int mi = 0; mi < 4; mi++) {
            int rowb = row0 + mi * 16 + quad * 4;
#pragma unroll
            for (int r = 0; r < 4; r++) {
                int row = rowb + r;
                if (row < N_NODES) {
                    f16x2 p;
                    p[0] = (_Float16)(acc[mi][ni][r] + brc);
                    p[1] = (_Float16)(acc[mi][ni + 2][r] + bic);
                    *reinterpret_cast<f16x2*>(H + row * 512 + 2 * c) = p;
                }
            }
        }
    }
}

// ---- evolve v4 (R7/R15-validated): interleaved h, NPB=60 / 512 threads /
// 500 blocks; coef precomputed by gemm's prep blocks; 2-deep software pipeline.
#define NPB 60
#define NGRP 8
__global__ __launch_bounds__(512) void k_evolve(
    const float* __restrict__ x, const int* __restrict__ sub_nodes,
    const float* __restrict__ c4, const _Float16* __restrict__ h,
    const float* __restrict__ escp,
    float* __restrict__ outz, _Float16* __restrict__ zbuf, int use_f16,
    float* __restrict__ ssum, float* __restrict__ ssumsq)
{
    __shared__ int   s_nodes[NPB][4];
    __shared__ float s_P[NPB][4];
    __shared__ float s_redA[NGRP][256];
    __shared__ float s_redB[NGRP][256];
    int tid = threadIdx.x;
    int g = tid >> 6, lane = tid & 63;
    int base = blockIdx.x * NPB;      // 30000 = 500*60 exactly
    if (tid < NPB) {
        int node = base + tid;
        *reinterpret_cast<float4*>(&s_P[tid][0]) =
            *reinterpret_cast<const float4*>(c4 + node * 4);
        *reinterpret_cast<int4*>(&s_nodes[tid][0]) =
            *reinterpret_cast<const int4*>(sub_nodes + node * 4);
    }
    __syncthreads();
    float esc = *escp;
    float lsum[4] = {0.f, 0.f, 0.f, 0.f};
    float lsq[4]  = {0.f, 0.f, 0.f, 0.f};

    f16x8 hvA[4];
    float4 xA;
    int j = g;
#pragma unroll
    for (int s = 0; s < 4; s++)
        hvA[s] = *reinterpret_cast<const f16x8*>(h + s_nodes[j][s] * 512 + lane * 8);
    xA = *reinterpret_cast<const float4*>(x + (base + j) * NC + lane * 4);

    for (;;) {
        int jn = j + NGRP;
        bool more = jn < NPB;
        f16x8 hvB[4];
        float4 xB;
        if (more) {
#pragma unroll
            for (int s = 0; s < 4; s++)
                hvB[s] = *reinterpret_cast<const f16x8*>(
                    h + s_nodes[jn][s] * 512 + lane * 8);
            xB = *reinterpret_cast<const float4*>(x + (base + jn) * NC + lane * 4);
        }
        // ---- compute node j from hvA/xA ----
        {
            int node = base + j;
            float P0 = s_P[j][0], P1 = s_P[j][1], P2 = s_P[j][2], P3 = s_P[j][3];
            float xr[4] = {xA.x, xA.y, xA.z, xA.w};
            f16x8 zo;
            float or4[4], oi4[4];
#pragma unroll
            for (int e = 0; e < 4; e++) {
                float hr0 = (float)hvA[0][2 * e], hi0 = (float)hvA[0][2 * e + 1];
                float hr1 = (float)hvA[1][2 * e], hi1 = (float)hvA[1][2 * e + 1];
                float hr2 = (float)hvA[2][2 * e], hi2 = (float)hvA[2][2 * e + 1];
                float hr3 = (float)hvA[3][2 * e], hi3 = (float)hvA[3][2 * e + 1];
                float er = esc * hr0;             // identity (self) term, m0==1
                float ei = esc * hi0;
                er = fmaf(P0, hi0, er); ei = fmaf(-P0, hr0, ei);
                er = fmaf(P1, hi1, er); ei = fmaf(-P1, hr1, ei);
                er = fmaf(P2, hi2, er); ei = fmaf(-P2, hr2, ei);
                er = fmaf(P3, hi3, er); ei = fmaf(-P3, hr3, ei);
                float outr = er + xr[e];
                float outi = ei;
                or4[e] = outr; oi4[e] = outi;
                zo[2 * e] = (_Float16)outr; zo[2 * e + 1] = (_Float16)outi;
                float mag = sqrtf(fmaf(outr, outr, fmaf(outi, outi, 1e-5f)));
                mag = fminf(fmaxf(mag, 1e-5f), 1000.f);
                lsum[e] += mag;
                lsq[e] = fmaf(mag, mag, lsq[e]);
            }
            if (use_f16) {
                *reinterpret_cast<f16x8*>(zbuf + node * 512 + lane * 8) = zo;
            } else {
                *reinterpret_cast<float4*>(outz + node * 512 + lane * 4) =
                    make_float4(or4[0], or4[1], or4[2], or4[3]);
                *reinterpret_cast<float4*>(outz + node * 512 + 256 + lane * 4) =
                    make_float4(oi4[0], oi4[1], oi4[2], oi4[3]);
            }
        }
        if (!more) break;
#pragma unroll
        for (int s = 0; s < 4; s++) hvA[s] = hvB[s];
        xA = xB;
        j = jn;
    }
#pragma unroll
    for (int e = 0; e < 4; e++) {
        s_redA[g][lane * 4 + e] = lsum[e];
        s_redB[g][lane * 4 + e] = lsq[e];
    }
    __syncthreads();
    if (tid < 256) {
        float a = 0.f;
#pragma unroll
        for (int q = 0; q < NGRP; q++) a += s_redA[q][tid];
        atomicAdd(&ssum[tid], a);          // tid == channel; 500 adds per address
    } else {
        int t = tid - 256;
        float b = 0.f;
#pragma unroll
        for (int q = 0; q < NGRP; q++) b += s_redB[q][t];
        atomicAdd(&ssumsq[t], b);
    }
}

// ---- layernorm + phase + leaky crelu; stats affine recomputed inline ----
__global__ __launch_bounds__(256) void k_norm(
    float* __restrict__ out, const _Float16* __restrict__ zbuf, int use_f16,
    const float* __restrict__ ssum, const float* __restrict__ ssumsq,
    const float* __restrict__ lnw, const float* __restrict__ lnb)
{
    int tid = threadIdx.x;
    int node = blockIdx.x * 4 + (tid >> 6);        // 7500 blocks
    int c0 = (tid & 63) * 4;
    float re[4], im[4];
    if (use_f16) {
        f16x8 z = *reinterpret_cast<const f16x8*>(zbuf + node * 512 + c0 * 2);
#pragma unroll
        for (int e = 0; e < 4; e++) { re[e] = (float)z[2 * e]; im[e] = (float)z[2 * e + 1]; }
    } else {
        float4 r4 = *reinterpret_cast<const float4*>(out + node * 512 + c0);
        float4 i4 = *reinterpret_cast<const float4*>(out + node * 512 + 256 + c0);
        re[0] = r4.x; re[1] = r4.y; re[2] = r4.z; re[3] = r4.w;
        im[0] = i4.x; im[1] = i4.y; im[2] = i4.z; im[3] = i4.w;
    }
    float4 s4 = *reinterpret_cast<const float4*>(ssum + c0);
    float4 q4 = *reinterpret_cast<const float4*>(ssumsq + c0);
    float4 w4 = *reinterpret_cast<const float4*>(lnw + c0);
    float4 lb4 = *reinterpret_cast<const float4*>(lnb + c0);
    float S[4] = {s4.x, s4.y, s4.z, s4.w};
    float Q[4] = {q4.x, q4.y, q4.z, q4.w};
    float W[4] = {w4.x, w4.y, w4.z, w4.w};
    float L[4] = {lb4.x, lb4.y, lb4.z, lb4.w};
    const float invN = 1.0f / (float)N_NODES;
    float orr[4], oii[4];
#pragma unroll
    for (int e = 0; e < 4; e++) {
        float mean = S[e] * invN;
        float var = fmaxf(Q[e] * invN - mean * mean, 0.f);
        float denom = sqrtf(var + 1e-5f) + 1e-5f;
        float A = fabsf(W[e]) / denom;
        float Bc = L[e] - mean * A;
        float r = re[e], i = im[e];
        float mag = sqrtf(fmaf(r, r, fmaf(i, i, 1e-5f)));
        mag = fminf(fmaxf(mag, 1e-5f), 1000.f);
        float sm = fmaf(mag, A, Bc);
        sm = fminf(fmaxf(sm, 1e-5f), 10.0f);
        float px = fminf(fmaxf(r, -1e6f), 1e6f) + 1e-10f;
        float py = fminf(fmaxf(i, -1e6f), 1e6f);
        float r2 = fmaf(px, px, py * py);
        float inv = rsqrtf(r2);
        float zr = sm * px * inv, zi = sm * py * inv;
        zr = fminf(fmaxf(zr, -5.f), 5.f);
        zi = fminf(fmaxf(zi, -5.f), 5.f);
        orr[e] = zr > 0.f ? zr : 0.01f * zr;
        oii[e] = zi > 0.f ? zi : 0.01f * zi;
    }
    *reinterpret_cast<float4*>(out + node * 512 + c0) =
        make_float4(orr[0], orr[1], orr[2], orr[3]);
    *reinterpret_cast<float4*>(out + node * 512 + 256 + c0) =
        make_float4(oii[0], oii[1], oii[2], oii[3]);
}

extern "C" void kernel_launch(void* const* d_in, const int* in_sizes, int n_in,
                              void* d_out, int out_size, void* d_ws, size_t ws_size,
                              hipStream_t stream) {
    const float* x        = (const float*)d_in[0];
    // d_in[1] edge_index: unused (sub_nodes/sub_mask/sub_H are precomputed)
    const int*   sub_nodes = (const int*)d_in[2];
    const float* sub_mask  = (const float*)d_in[3];
    const float* subH      = (const float*)d_in[4];
    const float* wr  = (const float*)d_in[5];
    const float* wi  = (const float*)d_in[6];
    const float* br  = (const float*)d_in[7];
    const float* bi  = (const float*)d_in[8];
    const float* lnw = (const float*)d_in[9];
    const float* lnb = (const float*)d_in[10];
    const float* esc = (const float*)d_in[11];
    float* out = (float*)d_out;

    char* ws = (char*)d_ws;
    const size_t H_OFF    = 0;                    // 30000*512*2  = 30,720,000
    const size_t STAT_OFF = 30720000;             // 2 * 1024 (alloc 4096)
    const size_t C4_OFF   = 30724096;             // 30000*16     =    480,000
    const size_t ZB_OFF   = 31204096;             // 30000*512*2  = 30,720,000 (optional)
    const size_t WS_NEED_F16 = ZB_OFF + 30720000; // 61,924,096
    _Float16* h  = (_Float16*)(ws + H_OFF);
    float* ssum   = (float*)(ws + STAT_OFF);
    float* ssumsq = (float*)(ws + STAT_OFF + 1024);
    float* c4     = (float*)(ws + C4_OFF);
    _Float16* zbuf = (_Float16*)(ws + ZB_OFF);
    int use_f16 = (ws_size >= WS_NEED_F16) ? 1 : 0;

    hipLaunchKernelGGL(k_gemm, dim3(NGB + NPREP + 1), dim3(256), 0, stream,
                       x, wr, wi, br, bi, h, subH, sub_mask, esc, c4,
                       ssum, ssumsq);
    hipLaunchKernelGGL(k_evolve, dim3(500), dim3(512), 0, stream,
                       x, sub_nodes, c4, h, esc, out, zbuf, use_f16,
                       ssum, ssumsq);
    hipLaunchKernelGGL(k_norm, dim3(7500), dim3(256), 0, stream,
                       out, zbuf, use_f16, ssum, ssumsq, lnw, lnb);
}

// Round 19
// 182.151 us; speedup vs baseline: 1.0498x; 1.0498x over previous
//
#include <hip/hip_runtime.h>
#include <stdint.h>

#define N_NODES 30000
#define NC 256

typedef _Float16 f16x8 __attribute__((ext_vector_type(8)));
typedef _Float16 f16x4 __attribute__((ext_vector_type(4)));
typedef _Float16 f16x2 __attribute__((ext_vector_type(2)));
typedef float f32x4 __attribute__((ext_vector_type(4)));

#define GLOAD_LDS16(g, l) __builtin_amdgcn_global_load_lds(                      \
    (const __attribute__((address_space(1))) void*)(g),                          \
    (__attribute__((address_space(3))) void*)(l), 16, 0, 0)

// ---- fused pre-pass: conv_x | conv_w | prep | stats-zero, branch on blockIdx.
// R4: fusion confirmed (-19us vs separate dispatches). R16 conclusion: doing
// the f32->f16 conversion here at pure HBM rate and letting gemm read f16 is
// ~12us cheaper than merging the conversion into gemm (R11/R15/R16 all ~51us
// gemm vs <=40us here) -- more than the one dispatch gap the merge saves.
#define NBX 7500
#define NBW 128
#define NBP 118
__global__ __launch_bounds__(256) void k_pre(
    const float* __restrict__ x, _Float16* __restrict__ xb,
    const float* __restrict__ wr, const float* __restrict__ wi,
    _Float16* __restrict__ Wb,
    const float* __restrict__ subH, const float* __restrict__ sub_mask,
    const float* __restrict__ escp, float* __restrict__ c4,
    float* __restrict__ ssum, float* __restrict__ ssumsq)
{
    int bid = blockIdx.x, tid = threadIdx.x;
    if (bid < NBX) {
        // conv_x: clip +-10, f32 -> f16
        int i = (bid * 256 + tid) * 4;            // 7,680,000 elements exact
        float4 v = *reinterpret_cast<const float4*>(x + i);
        f16x4 o;
        o[0] = (_Float16)fminf(fmaxf(v.x, -10.f), 10.f);
        o[1] = (_Float16)fminf(fmaxf(v.y, -10.f), 10.f);
        o[2] = (_Float16)fminf(fmaxf(v.z, -10.f), 10.f);
        o[3] = (_Float16)fminf(fmaxf(v.w, -10.f), 10.f);
        *reinterpret_cast<f16x4*>(xb + i) = o;
    } else if (bid < NBX + NBW) {
        // conv_w: [w_real; w_imag] -> f16 [512][256]
        int i = ((bid - NBX) * 256 + tid) * 4;    // 131,072 elements exact
        const float* src = (i < NC * NC) ? (wr + i) : (wi + (i - NC * NC));
        float4 v = *reinterpret_cast<const float4*>(src);
        f16x4 o;
        o[0] = (_Float16)v.x; o[1] = (_Float16)v.y;
        o[2] = (_Float16)v.z; o[3] = (_Float16)v.w;
        *reinterpret_cast<f16x4*>(Wb + i) = o;
    } else if (bid < NBX + NBW + NBP) {
        // prep: P_s = esc*1e-4*subH[0][s]*mask[s]/||H||_F (clamps provably fire)
        int node = (bid - NBX - NBW) * 256 + tid;
        if (node < N_NODES) {
            float esc = *escp;
            const float4* Hp = reinterpret_cast<const float4*>(subH + node * 16);
            float4 r0 = Hp[0], r1 = Hp[1], r2 = Hp[2], r3 = Hp[3];
            float fr = r0.x * r0.x + r0.y * r0.y + r0.z * r0.z + r0.w * r0.w
                     + r1.x * r1.x + r1.y * r1.y + r1.z * r1.z + r1.w * r1.w
                     + r2.x * r2.x + r2.y * r2.y + r2.z * r2.z + r2.w * r2.w
                     + r3.x * r3.x + r3.y * r3.y + r3.z * r3.z + r3.w * r3.w;
            float coef = 1e-4f * rsqrtf(fr) * esc;
            float4 m = *reinterpret_cast<const float4*>(sub_mask + node * 4);
            float4 o;
            o.x = coef * r0.x * m.x;
            o.y = coef * r0.y * m.y;
            o.z = coef * r0.z * m.z;
            o.w = coef * r0.w * m.w;
            *reinterpret_cast<float4*>(c4 + node * 4) = o;
        }
    } else {
        // stats zero (replaces hipMemsetAsync dispatch)
        ssum[tid] = 0.f;
        ssumsq[tid] = 0.f;
    }
}

// ---- GEMM v8 (R7-validated, best measured: <=40us, FETCH 15.6 MB): f16 A
// in-loop loads + B panel staged ONCE via global_load_lds w=16, XOR-swizzled.
__global__ __launch_bounds__(256, 2) void k_gemm(
    const _Float16* __restrict__ A, const _Float16* __restrict__ B,
    const float* __restrict__ br, const float* __restrict__ bi,
    _Float16* __restrict__ H)
{
    __shared__ _Float16 Bs[128 * 256];        // 64KB: rows 0..63 re, 64..127 im
    int bid = blockIdx.x;
    int bm = bid % 235;
    int cs = bid / 235;                       // 0..3 channel-groups of 64
    int tid = threadIdx.x;
    int wv = tid >> 6, ln = tid & 63;

    // ---- stage B panel: 16 issues of 4KB (wave-uniform LDS base + lane*16B).
    // Linear LDS byte (brow*512 + chunk*16) receives logical chunk ^ (brow&7):
    // pre-swizzle the SOURCE, swizzle the ds_read (both-sides rule).
#pragma unroll
    for (int i = 0; i < 16; i++) {
        int brow = i * 8 + wv * 2 + (ln >> 5);        // 0..127
        int chunk = ln & 31;                          // 16B units within row
        int Brow = (brow < 64) ? (cs * 64 + brow) : (256 + cs * 64 + brow - 64);
        int chl = chunk ^ (brow & 7);
        const _Float16* src = B + Brow * 256 + chl * 8;
        GLOAD_LDS16(src, &Bs[i * 2048 + wv * 512]);
    }

    int quad = ln >> 4, l16 = ln & 15;
    int wm = wv >> 1, wq = wv & 1;            // wave: 64 rows x 32 channels
    int row0 = bm * 128 + wm * 64;

    const _Float16* ap[4];
#pragma unroll
    for (int mi = 0; mi < 4; mi++) {
        int r = row0 + mi * 16 + l16;
        if (r >= N_NODES) r = N_NODES - 1;    // clamp: garbage rows never stored
        ap[mi] = A + r * NC + quad * 8;
    }
    // B-fragment LDS rows (f16 row stride 256): ni 0,1 re; 2,3 im (same channels)
    int brow_f[4];
#pragma unroll
    for (int ni = 0; ni < 4; ni++)
        brow_f[ni] = (ni < 2 ? 0 : 64) + wq * 32 + (ni & 1) * 16 + l16;

    __syncthreads();                          // drains the global_load_lds queue

    f32x4 acc[4][4] = {};
#pragma unroll
    for (int kc = 0; kc < 8; kc++) {
        f16x8 af[4];
#pragma unroll
        for (int mi = 0; mi < 4; mi++)
            af[mi] = *reinterpret_cast<const f16x8*>(ap[mi] + kc * 32);
        f16x8 bf[4];
#pragma unroll
        for (int ni = 0; ni < 4; ni++) {
            int ch = (quad + kc * 4) ^ (l16 & 7);     // brow&7 == l16&7
            bf[ni] = *reinterpret_cast<const f16x8*>(&Bs[brow_f[ni] * 256 + ch * 8]);
        }
#pragma unroll
        for (int mi = 0; mi < 4; mi++)
#pragma unroll
            for (int ni = 0; ni < 4; ni++)
                acc[mi][ni] = __builtin_amdgcn_mfma_f32_16x16x32_f16(
                    af[mi], bf[ni], acc[mi][ni], 0, 0, 0);
    }

    // ---- epilogue: pack (re, im) -> one 4B store, 64B contiguous per 16 lanes
#pragma unroll
    for (int ni = 0; ni < 2; ni++) {
        int c = cs * 64 + wq * 32 + ni * 16 + l16;    // channel 0..255
        float brc = br[c], bic = bi[c];
#pragma unroll
        for (int mi = 0; mi < 4; mi++) {
            int rowb = row0 + mi * 16 + quad * 4;
#pragma unroll
            for (int r = 0; r < 4; r++) {
                int row = rowb + r;
                if (row < N_NODES) {
                    f16x2 p;
                    p[0] = (_Float16)(acc[mi][ni][r] + brc);
                    p[1] = (_Float16)(acc[mi][ni + 2][r] + bic);
                    *reinterpret_cast<f16x2*>(H + row * 512 + 2 * c) = p;
                }
            }
        }
    }
}

// ---- evolve v4 (R7-validated): interleaved h, NPB=60 / 512 threads /
// 500 blocks; coef precomputed by k_pre; 2-deep software pipeline.
#define NPB 60
#define NGRP 8
__global__ __launch_bounds__(512) void k_evolve(
    const float* __restrict__ x, const int* __restrict__ sub_nodes,
    const float* __restrict__ c4, const _Float16* __restrict__ h,
    const float* __restrict__ escp,
    float* __restrict__ outz, _Float16* __restrict__ zbuf, int use_f16,
    float* __restrict__ ssum, float* __restrict__ ssumsq)
{
    __shared__ int   s_nodes[NPB][4];
    __shared__ float s_P[NPB][4];
    __shared__ float s_redA[NGRP][256];
    __shared__ float s_redB[NGRP][256];
    int tid = threadIdx.x;
    int g = tid >> 6, lane = tid & 63;
    int base = blockIdx.x * NPB;      // 30000 = 500*60 exactly
    if (tid < NPB) {
        int node = base + tid;
        *reinterpret_cast<float4*>(&s_P[tid][0]) =
            *reinterpret_cast<const float4*>(c4 + node * 4);
        *reinterpret_cast<int4*>(&s_nodes[tid][0]) =
            *reinterpret_cast<const int4*>(sub_nodes + node * 4);
    }
    __syncthreads();
    float esc = *escp;
    float lsum[4] = {0.f, 0.f, 0.f, 0.f};
    float lsq[4]  = {0.f, 0.f, 0.f, 0.f};

    f16x8 hvA[4];
    float4 xA;
    int j = g;
#pragma unroll
    for (int s = 0; s < 4; s++)
        hvA[s] = *reinterpret_cast<const f16x8*>(h + s_nodes[j][s] * 512 + lane * 8);
    xA = *reinterpret_cast<const float4*>(x + (base + j) * NC + lane * 4);

    for (;;) {
        int jn = j + NGRP;
        bool more = jn < NPB;
        f16x8 hvB[4];
        float4 xB;
        if (more) {
#pragma unroll
            for (int s = 0; s < 4; s++)
                hvB[s] = *reinterpret_cast<const f16x8*>(
                    h + s_nodes[jn][s] * 512 + lane * 8);
            xB = *reinterpret_cast<const float4*>(x + (base + jn) * NC + lane * 4);
        }
        // ---- compute node j from hvA/xA ----
        {
            int node = base + j;
            float P0 = s_P[j][0], P1 = s_P[j][1], P2 = s_P[j][2], P3 = s_P[j][3];
            float xr[4] = {xA.x, xA.y, xA.z, xA.w};
            f16x8 zo;
            float or4[4], oi4[4];
#pragma unroll
            for (int e = 0; e < 4; e++) {
                float hr0 = (float)hvA[0][2 * e], hi0 = (float)hvA[0][2 * e + 1];
                float hr1 = (float)hvA[1][2 * e], hi1 = (float)hvA[1][2 * e + 1];
                float hr2 = (float)hvA[2][2 * e], hi2 = (float)hvA[2][2 * e + 1];
                float hr3 = (float)hvA[3][2 * e], hi3 = (float)hvA[3][2 * e + 1];
                float er = esc * hr0;             // identity (self) term, m0==1
                float ei = esc * hi0;
                er = fmaf(P0, hi0, er); ei = fmaf(-P0, hr0, ei);
                er = fmaf(P1, hi1, er); ei = fmaf(-P1, hr1, ei);
                er = fmaf(P2, hi2, er); ei = fmaf(-P2, hr2, ei);
                er = fmaf(P3, hi3, er); ei = fmaf(-P3, hr3, ei);
                float outr = er + xr[e];
                float outi = ei;
                or4[e] = outr; oi4[e] = outi;
                zo[2 * e] = (_Float16)outr; zo[2 * e + 1] = (_Float16)outi;
                float mag = sqrtf(fmaf(outr, outr, fmaf(outi, outi, 1e-5f)));
                mag = fminf(fmaxf(mag, 1e-5f), 1000.f);
                lsum[e] += mag;
                lsq[e] = fmaf(mag, mag, lsq[e]);
            }
            if (use_f16) {
                *reinterpret_cast<f16x8*>(zbuf + node * 512 + lane * 8) = zo;
            } else {
                *reinterpret_cast<float4*>(outz + node * 512 + lane * 4) =
                    make_float4(or4[0], or4[1], or4[2], or4[3]);
                *reinterpret_cast<float4*>(outz + node * 512 + 256 + lane * 4) =
                    make_float4(oi4[0], oi4[1], oi4[2], oi4[3]);
            }
        }
        if (!more) break;
#pragma unroll
        for (int s = 0; s < 4; s++) hvA[s] = hvB[s];
        xA = xB;
        j = jn;
    }
#pragma unroll
    for (int e = 0; e < 4; e++) {
        s_redA[g][lane * 4 + e] = lsum[e];
        s_redB[g][lane * 4 + e] = lsq[e];
    }
    __syncthreads();
    if (tid < 256) {
        float a = 0.f;
#pragma unroll
        for (int q = 0; q < NGRP; q++) a += s_redA[q][tid];
        atomicAdd(&ssum[tid], a);          // tid == channel; 500 adds per address
    } else {
        int t = tid - 256;
        float b = 0.f;
#pragma unroll
        for (int q = 0; q < NGRP; q++) b += s_redB[q][t];
        atomicAdd(&ssumsq[t], b);
    }
}

// ---- layernorm + phase + leaky crelu; stats affine recomputed inline ----
__global__ __launch_bounds__(256) void k_norm(
    float* __restrict__ out, const _Float16* __restrict__ zbuf, int use_f16,
    const float* __restrict__ ssum, const float* __restrict__ ssumsq,
    const float* __restrict__ lnw, const float* __restrict__ lnb)
{
    int tid = threadIdx.x;
    int node = blockIdx.x * 4 + (tid >> 6);        // 7500 blocks
    int c0 = (tid & 63) * 4;
    float re[4], im[4];
    if (use_f16) {
        f16x8 z = *reinterpret_cast<const f16x8*>(zbuf + node * 512 + c0 * 2);
#pragma unroll
        for (int e = 0; e < 4; e++) { re[e] = (float)z[2 * e]; im[e] = (float)z[2 * e + 1]; }
    } else {
        float4 r4 = *reinterpret_cast<const float4*>(out + node * 512 + c0);
        float4 i4 = *reinterpret_cast<const float4*>(out + node * 512 + 256 + c0);
        re[0] = r4.x; re[1] = r4.y; re[2] = r4.z; re[3] = r4.w;
        im[0] = i4.x; im[1] = i4.y; im[2] = i4.z; im[3] = i4.w;
    }
    float4 s4 = *reinterpret_cast<const float4*>(ssum + c0);
    float4 q4 = *reinterpret_cast<const float4*>(ssumsq + c0);
    float4 w4 = *reinterpret_cast<const float4*>(lnw + c0);
    float4 lb4 = *reinterpret_cast<const float4*>(lnb + c0);
    float S[4] = {s4.x, s4.y, s4.z, s4.w};
    float Q[4] = {q4.x, q4.y, q4.z, q4.w};
    float W[4] = {w4.x, w4.y, w4.z, w4.w};
    float L[4] = {lb4.x, lb4.y, lb4.z, lb4.w};
    const float invN = 1.0f / (float)N_NODES;
    float orr[4], oii[4];
#pragma unroll
    for (int e = 0; e < 4; e++) {
        float mean = S[e] * invN;
        float var = fmaxf(Q[e] * invN - mean * mean, 0.f);
        float denom = sqrtf(var + 1e-5f) + 1e-5f;
        float A = fabsf(W[e]) / denom;
        float Bc = L[e] - mean * A;
        float r = re[e], i = im[e];
        float mag = sqrtf(fmaf(r, r, fmaf(i, i, 1e-5f)));
        mag = fminf(fmaxf(mag, 1e-5f), 1000.f);
        float sm = fmaf(mag, A, Bc);
        sm = fminf(fmaxf(sm, 1e-5f), 10.0f);
        float px = fminf(fmaxf(r, -1e6f), 1e6f) + 1e-10f;
        float py = fminf(fmaxf(i, -1e6f), 1e6f);
        float r2 = fmaf(px, px, py * py);
        float inv = rsqrtf(r2);
        float zr = sm * px * inv, zi = sm * py * inv;
        zr = fminf(fmaxf(zr, -5.f), 5.f);
        zi = fminf(fmaxf(zi, -5.f), 5.f);
        orr[e] = zr > 0.f ? zr : 0.01f * zr;
        oii[e] = zi > 0.f ? zi : 0.01f * zi;
    }
    *reinterpret_cast<float4*>(out + node * 512 + c0) =
        make_float4(orr[0], orr[1], orr[2], orr[3]);
    *reinterpret_cast<float4*>(out + node * 512 + 256 + c0) =
        make_float4(oii[0], oii[1], oii[2], oii[3]);
}

extern "C" void kernel_launch(void* const* d_in, const int* in_sizes, int n_in,
                              void* d_out, int out_size, void* d_ws, size_t ws_size,
                              hipStream_t stream) {
    const float* x        = (const float*)d_in[0];
    // d_in[1] edge_index: unused (sub_nodes/sub_mask/sub_H are precomputed)
    const int*   sub_nodes = (const int*)d_in[2];
    const float* sub_mask  = (const float*)d_in[3];
    const float* subH      = (const float*)d_in[4];
    const float* wr  = (const float*)d_in[5];
    const float* wi  = (const float*)d_in[6];
    const float* br  = (const float*)d_in[7];
    const float* bi  = (const float*)d_in[8];
    const float* lnw = (const float*)d_in[9];
    const float* lnb = (const float*)d_in[10];
    const float* esc = (const float*)d_in[11];
    float* out = (float*)d_out;

    char* ws = (char*)d_ws;
    const size_t XB_OFF   = 0;                    // 30000*256*2  = 15,360,000
    const size_t WB_OFF   = 15360000;             // 512*256*2    =    262,144
    const size_t H_OFF    = 15622144;             // 30000*512*2  = 30,720,000
    const size_t STAT_OFF = 46342144;             // 2 * 1024 (alloc 4096)
    const size_t C4_OFF   = 46346240;             // 30000*16     =    480,000
    const size_t ZB_OFF   = 46826240;             // 30000*512*2  = 30,720,000 (optional)
    const size_t WS_NEED_F16 = ZB_OFF + 30720000; // 77,546,240
    _Float16* xb = (_Float16*)(ws + XB_OFF);
    _Float16* Wb = (_Float16*)(ws + WB_OFF);
    _Float16* h  = (_Float16*)(ws + H_OFF);
    float* ssum   = (float*)(ws + STAT_OFF);
    float* ssumsq = (float*)(ws + STAT_OFF + 1024);
    float* c4     = (float*)(ws + C4_OFF);
    _Float16* zbuf = (_Float16*)(ws + ZB_OFF);
    int use_f16 = (ws_size >= WS_NEED_F16) ? 1 : 0;

    hipLaunchKernelGGL(k_pre, dim3(NBX + NBW + NBP + 1), dim3(256), 0, stream,
                       x, xb, wr, wi, Wb, subH, sub_mask, esc, c4, ssum, ssumsq);
    hipLaunchKernelGGL(k_gemm, dim3(235 * 4), dim3(256), 0, stream, xb, Wb, br, bi, h);
    hipLaunchKernelGGL(k_evolve, dim3(500), dim3(512), 0, stream,
                       x, sub_nodes, c4, h, esc, out, zbuf, use_f16,
                       ssum, ssumsq);
    hipLaunchKernelGGL(k_norm, dim3(7500), dim3(256), 0, stream,
                       out, zbuf, use_f16, ssum, ssumsq, lnw, lnb);
}